// Round 1
// baseline (1378.125 us; speedup 1.0000x reference)
//
#include <hip/hip_runtime.h>

#define B_N 512
#define V_N 32768
#define C_N 16

static constexpr float K_LERP = 2.0f / 1001.0f;  // 1 - MOMENTUM

// Kernel A: bucket sample indices by class. One wave per class; ballot-compact.
__global__ __launch_bounds__(64) void bucket_kernel(const int* __restrict__ labels,
                                                    int* __restrict__ lists,
                                                    int* __restrict__ counts) {
    const int c = blockIdx.x;
    const int lane = threadIdx.x;  // 0..63
    int n = 0;
    for (int base = 0; base < B_N; base += 64) {
        const int b = base + lane;
        const bool mine = (labels[b] == c);
        const unsigned long long m = __ballot(mine);
        const int pos = n + __popcll(m & ((1ull << lane) - 1ull));
        if (mine) lists[c * B_N + pos] = b;
        n += __popcll(m);
    }
    if (lane == 0) counts[c] = n;
}

// Kernel B: one (v-tile, class) block streams the class's samples once.
// Each thread owns 2 consecutive v. Sparse read is a coalesced float2;
// W reads are 4B gathers at stride 64B (one demanded line per lane — the
// unavoidable 1 GiB of W traffic).
__global__ __launch_bounds__(256) void centroid_kernel(
    const float* __restrict__ sparse, const float* __restrict__ W,
    const float* __restrict__ centroids, const int* __restrict__ initialized,
    const int* __restrict__ lists, const int* __restrict__ counts,
    float* __restrict__ out) {
    const int c = blockIdx.y;
    const int v0 = (blockIdx.x * 256 + threadIdx.x) * 2;

    __shared__ int lds_list[B_N];
    const int n = counts[c];
    for (int i = threadIdx.x; i < n; i += 256) lds_list[i] = lists[c * B_N + i];
    __syncthreads();

    float acc0 = 0.0f, acc1 = 0.0f;
#pragma unroll 4
    for (int i = 0; i < n; ++i) {
        // b is identical across the wave; force it scalar for SGPR base addressing
        const int b = __builtin_amdgcn_readfirstlane(lds_list[i]);
        const int sidx = b * V_N + v0;
        const float2 s = *reinterpret_cast<const float2*>(sparse + sidx);
        const float w0 = W[sidx * C_N + c];
        const float w1 = W[(sidx + 1) * C_N + c];
        acc0 += fabsf(s.x * w0);
        acc1 += fabsf(s.y * w1);
    }

    const float2 cen = *reinterpret_cast<const float2*>(centroids + c * V_N + v0);
    float r0, r1;
    if (n == 0) {
        r0 = cen.x;
        r1 = cen.y;
    } else {
        const float inv = 1.0f / (float)n;
        const float m0 = acc0 * inv;
        const float m1 = acc1 * inv;
        if (initialized[c] != 0) {
            r0 = cen.x + K_LERP * (m0 - cen.x);
            r1 = cen.y + K_LERP * (m1 - cen.y);
        } else {
            r0 = m0;
            r1 = m1;
        }
    }
    *reinterpret_cast<float2*>(out + c * V_N + v0) = make_float2(r0, r1);
}

extern "C" void kernel_launch(void* const* d_in, const int* in_sizes, int n_in,
                              void* d_out, int out_size, void* d_ws, size_t ws_size,
                              hipStream_t stream) {
    const float* sparse      = (const float*)d_in[0];
    const float* W           = (const float*)d_in[1];
    const int*   labels      = (const int*)d_in[2];
    const float* centroids   = (const float*)d_in[3];
    const int*   initialized = (const int*)d_in[4];
    float* out = (float*)d_out;

    int* lists  = (int*)d_ws;            // [C_N * B_N]
    int* counts = lists + C_N * B_N;     // [C_N]

    bucket_kernel<<<dim3(C_N), dim3(64), 0, stream>>>(labels, lists, counts);
    centroid_kernel<<<dim3(V_N / 512, C_N), dim3(256), 0, stream>>>(
        sparse, W, centroids, initialized, lists, counts, out);
}